// Round 9
// baseline (31.311 us; speedup 1.0000x reference)
//
#include <hip/hip_runtime.h>
#include <math.h>

// Problem constants (fixed by reference setup_inputs)
constexpr int B = 64;
constexpr int S = 1024;
constexpr int D = 256;
constexpr int NNEG = 32;
constexpr int GPB = 64;                 // groups (blocks) per chain in K1
constexpr int G1 = B * GPB;             // 4096 partial blocks
constexpr int RPB = S / GPB;            // 16 rows per K1 block
constexpr int NPAIR = B * (B - 1) / 2;  // 2016

typedef unsigned int u32;

// async 16B/lane global->LDS DMA: lane i's 16B lands at ldsbase + i*16.
__device__ __forceinline__ void stage16(const float* g, float* l) {
    __builtin_amdgcn_global_load_lds(
        (__attribute__((address_space(1))) u32*)(g),
        (__attribute__((address_space(3))) u32*)(l),
        16, 0, 0);
}

// ================= K1: 16-row partials via global_load_lds staging ===========
// 4096 blocks x 256 thr (4 waves). Wave w stages+computes rows w*4..w*4+3.
// Block 4096: hard-negative row means + zeroes the k2fin counter.
__global__ __launch_bounds__(256, 8) void k1(const float* __restrict__ x,
                                             const float* __restrict__ neg,
                                             float* __restrict__ pblk,
                                             float* __restrict__ praw,
                                             float* __restrict__ lnn,
                                             int* __restrict__ ctr) {
    const int blk  = blockIdx.x;
    const int t    = threadIdx.x;
    const int wave = t >> 6;            // 0..3
    const int lane = t & 63;

    if (blk == G1) {
        __shared__ float nn8[NNEG][8];
        if (t == 0) ctr[0] = 0;               // reset k2fin's arrival counter
        const int k = t >> 3, part = t & 7;   // 32 rows x 8 parts
        const float4* p4 = (const float4*)(neg + k * D + part * 32);
        float s = 0.f;
        #pragma unroll
        for (int e = 0; e < 8; ++e) {
            const float4 v = p4[e];
            s += v.x + v.y + v.z + v.w;
        }
        nn8[k][part] = s;
        __syncthreads();
        if (t < NNEG) {
            float ss = 0.f;
            #pragma unroll
            for (int e = 0; e < 8; ++e) ss += nn8[t][e];
            lnn[t] = ss / (float)D;
        }
        return;
    }

    __shared__ float rows[RPB][D];      // 16 KB, LINEAR (gload_lds requirement)
    __shared__ float sps[4];

    const int b = blk >> 6;             // chain
    const int g = blk & 63;             // group of 16 rows
    const float* src = x + ((size_t)b * S + (size_t)g * RPB + wave * 4) * D + lane * 4;

    // issue 4 async 1KB row loads (per wave) -> up to 128KB/CU in flight
    #pragma unroll
    for (int i = 0; i < 4; ++i) stage16(src + (size_t)i * D, &rows[wave * 4 + i][0]);

    __syncthreads();   // s_waitcnt vmcnt(0) + barrier: rows[] ready

    const float4 v0 = *(const float4*)&rows[wave * 4 + 0][lane * 4];
    const float4 v1 = *(const float4*)&rows[wave * 4 + 1][lane * 4];
    const float4 v2 = *(const float4*)&rows[wave * 4 + 2][lane * 4];
    const float4 v3 = *(const float4*)&rows[wave * 4 + 3][lane * 4];

    float s0 = v0.x * v0.x + v0.y * v0.y + v0.z * v0.z + v0.w * v0.w;
    float s1 = v1.x * v1.x + v1.y * v1.y + v1.z * v1.z + v1.w * v1.w;
    float s2 = v2.x * v2.x + v2.y * v2.y + v2.z * v2.z + v2.w * v2.w;
    float s3 = v3.x * v3.x + v3.y * v3.y + v3.z * v3.z + v3.w * v3.w;
    #pragma unroll
    for (int m = 1; m < 64; m <<= 1) {
        s0 += __shfl_xor(s0, m, 64);
        s1 += __shfl_xor(s1, m, 64);
        s2 += __shfl_xor(s2, m, 64);
        s3 += __shfl_xor(s3, m, 64);
    }
    // 1/max(sqrt(ss),1e-8) == rsq(max(ss,1e-16)); single v_rsq_f32
    const float i0 = __builtin_amdgcn_rsqf(fmaxf(s0, 1e-16f));
    const float i1 = __builtin_amdgcn_rsqf(fmaxf(s1, 1e-16f));
    const float i2 = __builtin_amdgcn_rsqf(fmaxf(s2, 1e-16f));
    const float i3 = __builtin_amdgcn_rsqf(fmaxf(s3, 1e-16f));

    float4 a;
    a.x = v0.x * i0 + v1.x * i1 + v2.x * i2 + v3.x * i3;
    a.y = v0.y * i0 + v1.y * i1 + v2.y * i2 + v3.y * i3;
    a.z = v0.z * i0 + v1.z * i1 + v2.z * i2 + v3.z * i3;
    a.w = v0.w * i0 + v1.w * i1 + v2.w * i2 + v3.w * i3;
    float ps = (v0.x + v0.y + v0.z + v0.w) + (v1.x + v1.y + v1.z + v1.w) +
               (v2.x + v2.y + v2.z + v2.w) + (v3.x + v3.y + v3.z + v3.w);
    #pragma unroll
    for (int m = 1; m < 64; m <<= 1) ps += __shfl_xor(ps, m, 64);

    // reuse rows[] for the cross-wave column combine (own rows only -> no race)
    *(float4*)&rows[wave * 4][lane * 4] = a;
    if (lane == 0) sps[wave] = ps;
    __syncthreads();

    pblk[(size_t)blk * D + t] = rows[0][t] + rows[4][t] + rows[8][t] + rows[12][t];
    if (t == 0) praw[blk] = sps[0] + sps[1] + sps[2] + sps[3];
}

// ================= K1b: chain reduce -> cs, sq, pm ===========================
// 64 blocks x 256 thr; thread t = dim t.
__global__ __launch_bounds__(256) void k1b(const float* __restrict__ pblk,
                                           const float* __restrict__ praw,
                                           float* __restrict__ cs,
                                           float* __restrict__ sq,
                                           float* __restrict__ pm) {
    const int b    = blockIdx.x;
    const int t    = threadIdx.x;
    const int wave = t >> 6;
    const int lane = t & 63;

    __shared__ float red[4];

    float v = 0.f;
    #pragma unroll 16
    for (int g = 0; g < GPB; ++g) v += pblk[(size_t)(b * GPB + g) * D + t];
    cs[(size_t)b * D + t] = v;

    float s2 = v * v;
    #pragma unroll
    for (int m = 1; m < 64; m <<= 1) s2 += __shfl_xor(s2, m, 64);
    if (lane == 0) red[wave] = s2;
    __syncthreads();
    if (t == 0) sq[b] = red[0] + red[1] + red[2] + red[3];

    if (wave == 0) {
        float s = praw[b * GPB + lane];                 // GPB == 64 == wave width
        #pragma unroll
        for (int m = 1; m < 64; m <<= 1) s += __shfl_xor(s, m, 64);
        if (lane == 0) pm[b] = s / (float)(S * D);
    }
}

// ================= K2fin: Gram row + last-block finalize =====================
__device__ __forceinline__ float block_sum256(float v, volatile float* red,
                                              int wave, int lane) {
    #pragma unroll
    for (int m = 1; m < 64; m <<= 1) v += __shfl_xor(v, m, 64);
    if (lane == 0) red[wave] = v;
    __syncthreads();
    v = red[0] + red[1] + red[2] + red[3];
    __syncthreads();
    return v;
}

__global__ __launch_bounds__(256) void k2fin(const float* __restrict__ cs,
                                             const float* __restrict__ sq,
                                             const float* __restrict__ pm,
                                             const float* __restrict__ lnn,
                                             float* __restrict__ inter_part,
                                             int* __restrict__ ctr,
                                             float* __restrict__ out) {
    const int b    = blockIdx.x;
    const int t    = threadIdx.x;
    const int wave = t >> 6;
    const int lane = t & 63;

    __shared__ float red[4];
    __shared__ int   role;

    // Gram row b: waves stride over columns j > b
    {
        const float invS2 = 1.0f / ((float)S * (float)S);
        const float4 a = *(const float4*)(cs + (size_t)b * D + lane * 4);
        float my = 0.f;
        for (int j = b + 1 + wave; j < B; j += 4) {
            const float4 bb = *(const float4*)(cs + (size_t)j * D + lane * 4);
            float dot = a.x * bb.x + a.y * bb.y + a.z * bb.z + a.w * bb.w;
            #pragma unroll
            for (int m = 1; m < 64; m <<= 1) dot += __shfl_xor(dot, m, 64);
            my += fminf(dot * invS2, 1.0f);
        }
        if (lane == 0) red[wave] = my;
        __syncthreads();
        if (t == 0) inter_part[b] = red[0] + red[1] + red[2] + red[3];
        __syncthreads();
    }

    // last-block handoff (single atomic per block, no spin)
    if (t == 0) {
        __threadfence();  // release our inter_part store device-wide
        const int old = __hip_atomic_fetch_add(ctr, 1, __ATOMIC_ACQ_REL,
                                               __HIP_MEMORY_SCOPE_AGENT);
        role = (old == B - 1) ? 1 : 0;
    }
    __syncthreads();
    if (!role) return;

    // ---- finalize (winner block only; values independent of winner id) ----
    float my_inter = 0.f, my_intra = 0.f;
    if (t < B) {
        my_inter = inter_part[t];
        my_intra = fminf((sq[t] - (float)S) / ((float)S * (float)(S - 1)), 1.0f);
    }

    float my_hard = 0.f;
    for (int k = t; k < B * NNEG; k += 256) {
        const int bb = k >> 5, nk = k & 31;
        my_hard += fmaxf(lnn[nk] - pm[bb] + 1.0f, 0.f);
    }

    const float intra = block_sum256(my_intra, red, wave, lane) / (float)B;
    const float inter = block_sum256(my_inter, red, wave, lane) / (float)NPAIR;
    const float hard  = block_sum256(my_hard,  red, wave, lane) / (float)(B * NNEG);

    if (t == 0) {
        out[0] = intra;
        out[1] = inter;
        out[2] = hard;
        out[3] = intra + inter + 0.1f * hard;
    }
}

extern "C" void kernel_launch(void* const* d_in, const int* in_sizes, int n_in,
                              void* d_out, int out_size, void* d_ws, size_t ws_size,
                              hipStream_t stream) {
    const float* x   = (const float*)d_in[0];   // [B, S, D]
    const float* neg = (const float*)d_in[1];   // [NNEG, D]
    float* out = (float*)d_out;

    int*   ctr = (int*)d_ws;                    // zeroed by k1's extra block
    float* wf  = (float*)((char*)d_ws + 256);
    float* pblk       = wf;                          // G1*D = 1048576
    float* praw       = pblk + (size_t)G1 * D;       // G1
    float* cs         = praw + G1;                   // B*D
    float* sq         = cs + (size_t)B * D;          // B
    float* pm         = sq + B;                      // B
    float* lnn        = pm + B;                      // NNEG
    float* inter_part = lnn + NNEG;                  // B

    k1<<<G1 + 1, 256, 0, stream>>>(x, neg, pblk, praw, lnn, ctr);
    k1b<<<B, 256, 0, stream>>>(pblk, praw, cs, sq, pm);
    k2fin<<<B, 256, 0, stream>>>(cs, sq, pm, lnn, inter_part, ctr, out);
}

// Round 10
// 26.818 us; speedup vs baseline: 1.1676x; 1.1676x over previous
//
#include <hip/hip_runtime.h>
#include <math.h>

// Problem constants (fixed by reference setup_inputs)
constexpr int B = 64;
constexpr int S = 1024;
constexpr int D = 256;
constexpr int NNEG = 32;
constexpr int GPB = 32;                 // groups (blocks) per chain in K1
constexpr int G1 = B * GPB;             // 2048 partial blocks
constexpr int RPB = S / GPB;            // 32 rows per K1 block
constexpr int NPAIR = B * (B - 1) / 2;  // 2016

// ---- DPP wave64 sum: 6 VALU ops, zero DS-pipe traffic ----
template <int CTRL, int RM>
__device__ __forceinline__ float dppadd(float v) {
    return v + __int_as_float(__builtin_amdgcn_update_dpp(
                   0, __float_as_int(v), CTRL, RM, 0xf, true));
}
// returns the 64-lane total as a wave-uniform (SGPR) value
__device__ __forceinline__ float wave_sum_dpp(float v) {
    v = dppadd<0x111, 0xf>(v);   // row_shr:1
    v = dppadd<0x112, 0xf>(v);   // row_shr:2
    v = dppadd<0x114, 0xf>(v);   // row_shr:4
    v = dppadd<0x118, 0xf>(v);   // row_shr:8  -> lane15 of each row16 = row sum
    v = dppadd<0x142, 0xa>(v);   // row_bcast:15 into rows 1,3
    v = dppadd<0x143, 0xc>(v);   // row_bcast:31 into rows 2,3 -> lane63 = total
    return __int_as_float(__builtin_amdgcn_readlane(__float_as_int(v), 63));
}

// ================= K1: 32-row partial sums, DPP row-norms ====================
// 2048 blocks x 256 thr (4 waves). Wave w: 8 rows, 4-row unroll x2.
// Block 2048: hard-negative row means + zeroes the k2fin counter.
__global__ __launch_bounds__(256) void k1(const float* __restrict__ x,
                                          const float* __restrict__ neg,
                                          float* __restrict__ pblk,
                                          float* __restrict__ praw,
                                          float* __restrict__ lnn,
                                          int* __restrict__ ctr) {
    const int blk  = blockIdx.x;
    const int t    = threadIdx.x;
    const int wave = t >> 6;            // 0..3
    const int lane = t & 63;

    if (blk == G1) {
        __shared__ float nn8[NNEG][8];
        if (t == 0) ctr[0] = 0;               // reset k2fin's arrival counter
        const int k = t >> 3, part = t & 7;   // 32 rows x 8 parts
        const float4* p4 = (const float4*)(neg + k * D + part * 32);
        float s = 0.f;
        #pragma unroll
        for (int e = 0; e < 8; ++e) {
            const float4 v = p4[e];
            s += v.x + v.y + v.z + v.w;
        }
        nn8[k][part] = s;
        __syncthreads();
        if (t < NNEG) {
            float ss = 0.f;
            #pragma unroll
            for (int e = 0; e < 8; ++e) ss += nn8[t][e];
            lnn[t] = ss / (float)D;
        }
        return;
    }

    __shared__ float sacc[4][D + 4];
    __shared__ float sps[4];

    const int b = blk >> 5;             // chain
    const int g = blk & 31;             // group of 32 rows
    const float* rowp = x + ((size_t)b * S + (size_t)g * RPB + wave * 8) * D + lane * 4;

    float ax = 0.f, ay = 0.f, az = 0.f, aw = 0.f, ps = 0.f;
    #pragma unroll
    for (int i = 0; i < 8; i += 4) {
        const float4 v0 = *(const float4*)(rowp + (size_t)(i + 0) * D);
        const float4 v1 = *(const float4*)(rowp + (size_t)(i + 1) * D);
        const float4 v2 = *(const float4*)(rowp + (size_t)(i + 2) * D);
        const float4 v3 = *(const float4*)(rowp + (size_t)(i + 3) * D);

        // per-row sum of squares via DPP (VALU-only, no DS pipe)
        const float s0 = wave_sum_dpp(v0.x * v0.x + v0.y * v0.y + v0.z * v0.z + v0.w * v0.w);
        const float s1 = wave_sum_dpp(v1.x * v1.x + v1.y * v1.y + v1.z * v1.z + v1.w * v1.w);
        const float s2 = wave_sum_dpp(v2.x * v2.x + v2.y * v2.y + v2.z * v2.z + v2.w * v2.w);
        const float s3 = wave_sum_dpp(v3.x * v3.x + v3.y * v3.y + v3.z * v3.z + v3.w * v3.w);

        // 1/max(sqrt(ss),1e-8) == rsq(max(ss,1e-16)); single v_rsq_f32
        const float i0 = __builtin_amdgcn_rsqf(fmaxf(s0, 1e-16f));
        const float i1 = __builtin_amdgcn_rsqf(fmaxf(s1, 1e-16f));
        const float i2 = __builtin_amdgcn_rsqf(fmaxf(s2, 1e-16f));
        const float i3 = __builtin_amdgcn_rsqf(fmaxf(s3, 1e-16f));

        ax += v0.x * i0 + v1.x * i1 + v2.x * i2 + v3.x * i3;
        ay += v0.y * i0 + v1.y * i1 + v2.y * i2 + v3.y * i3;
        az += v0.z * i0 + v1.z * i1 + v2.z * i2 + v3.z * i3;
        aw += v0.w * i0 + v1.w * i1 + v2.w * i2 + v3.w * i3;
        ps += (v0.x + v0.y + v0.z + v0.w) + (v1.x + v1.y + v1.z + v1.w) +
              (v2.x + v2.y + v2.z + v2.w) + (v3.x + v3.y + v3.z + v3.w);
    }

    *(float4*)&sacc[wave][lane * 4] = make_float4(ax, ay, az, aw);
    const float pst = wave_sum_dpp(ps);
    if (lane == 0) sps[wave] = pst;
    __syncthreads();

    {
        const float v = sacc[0][t] + sacc[1][t] + sacc[2][t] + sacc[3][t];
        pblk[(size_t)blk * D + t] = v;
    }
    if (t == 0) praw[blk] = sps[0] + sps[1] + sps[2] + sps[3];
}

// ================= K1b: chain reduce -> cs, sq, pm ===========================
// 64 blocks x 256 thr; thread t = dim t.
__global__ __launch_bounds__(256) void k1b(const float* __restrict__ pblk,
                                           const float* __restrict__ praw,
                                           float* __restrict__ cs,
                                           float* __restrict__ sq,
                                           float* __restrict__ pm) {
    const int b    = blockIdx.x;
    const int t    = threadIdx.x;
    const int wave = t >> 6;
    const int lane = t & 63;

    __shared__ float red[4];

    float v = 0.f;
    #pragma unroll
    for (int g = 0; g < GPB; ++g) v += pblk[(size_t)(b * GPB + g) * D + t];
    cs[(size_t)b * D + t] = v;

    const float s2 = wave_sum_dpp(v * v);
    if (lane == 0) red[wave] = s2;
    __syncthreads();
    if (t == 0) sq[b] = red[0] + red[1] + red[2] + red[3];

    if (wave == 0) {
        float s = (lane < GPB) ? praw[b * GPB + lane] : 0.f;
        const float tot = wave_sum_dpp(s);
        if (lane == 0) pm[b] = tot / (float)(S * D);
    }
}

// ================= K2fin: Gram row + last-block finalize =====================
__device__ __forceinline__ float block_sum256(float v, volatile float* red,
                                              int wave, int lane) {
    const float w = wave_sum_dpp(v);
    if (lane == 0) red[wave] = w;
    __syncthreads();
    const float r = red[0] + red[1] + red[2] + red[3];
    __syncthreads();
    return r;
}

__global__ __launch_bounds__(256) void k2fin(const float* __restrict__ cs,
                                             const float* __restrict__ sq,
                                             const float* __restrict__ pm,
                                             const float* __restrict__ lnn,
                                             float* __restrict__ inter_part,
                                             int* __restrict__ ctr,
                                             float* __restrict__ out) {
    const int b    = blockIdx.x;
    const int t    = threadIdx.x;
    const int wave = t >> 6;
    const int lane = t & 63;

    __shared__ float red[4];
    __shared__ int   role;

    // Gram row b: waves stride over columns j > b
    {
        const float invS2 = 1.0f / ((float)S * (float)S);
        const float4 a = *(const float4*)(cs + (size_t)b * D + lane * 4);
        float my = 0.f;
        for (int j = b + 1 + wave; j < B; j += 4) {
            const float4 bb = *(const float4*)(cs + (size_t)j * D + lane * 4);
            const float dot = wave_sum_dpp(a.x * bb.x + a.y * bb.y +
                                           a.z * bb.z + a.w * bb.w);
            my += fminf(dot * invS2, 1.0f);
        }
        // my is wave-uniform (built from uniform dots)
        if (lane == 0) red[wave] = my;
        __syncthreads();
        if (t == 0) inter_part[b] = red[0] + red[1] + red[2] + red[3];
        __syncthreads();
    }

    // last-block handoff (single atomic per block, no spin)
    if (t == 0) {
        __threadfence();  // release our inter_part store device-wide
        const int old = __hip_atomic_fetch_add(ctr, 1, __ATOMIC_ACQ_REL,
                                               __HIP_MEMORY_SCOPE_AGENT);
        role = (old == B - 1) ? 1 : 0;
    }
    __syncthreads();
    if (!role) return;

    // ---- finalize (winner block only; values independent of winner id) ----
    float my_inter = 0.f, my_intra = 0.f;
    if (t < B) {
        my_inter = inter_part[t];
        my_intra = fminf((sq[t] - (float)S) / ((float)S * (float)(S - 1)), 1.0f);
    }

    float my_hard = 0.f;
    for (int k = t; k < B * NNEG; k += 256) {
        const int bb = k >> 5, nk = k & 31;
        my_hard += fmaxf(lnn[nk] - pm[bb] + 1.0f, 0.f);
    }

    const float intra = block_sum256(my_intra, red, wave, lane) / (float)B;
    const float inter = block_sum256(my_inter, red, wave, lane) / (float)NPAIR;
    const float hard  = block_sum256(my_hard,  red, wave, lane) / (float)(B * NNEG);

    if (t == 0) {
        out[0] = intra;
        out[1] = inter;
        out[2] = hard;
        out[3] = intra + inter + 0.1f * hard;
    }
}

extern "C" void kernel_launch(void* const* d_in, const int* in_sizes, int n_in,
                              void* d_out, int out_size, void* d_ws, size_t ws_size,
                              hipStream_t stream) {
    const float* x   = (const float*)d_in[0];   // [B, S, D]
    const float* neg = (const float*)d_in[1];   // [NNEG, D]
    float* out = (float*)d_out;

    int*   ctr = (int*)d_ws;                    // zeroed by k1's extra block
    float* wf  = (float*)((char*)d_ws + 256);
    float* pblk       = wf;                          // G1*D = 524288
    float* praw       = pblk + (size_t)G1 * D;       // G1
    float* cs         = praw + G1;                   // B*D
    float* sq         = cs + (size_t)B * D;          // B
    float* pm         = sq + B;                      // B
    float* lnn        = pm + B;                      // NNEG
    float* inter_part = lnn + NNEG;                  // B

    k1<<<G1 + 1, 256, 0, stream>>>(x, neg, pblk, praw, lnn, ctr);
    k1b<<<B, 256, 0, stream>>>(pblk, praw, cs, sq, pm);
    k2fin<<<B, 256, 0, stream>>>(cs, sq, pm, lnn, inter_part, ctr, out);
}

// Round 11
// 26.773 us; speedup vs baseline: 1.1695x; 1.0017x over previous
//
#include <hip/hip_runtime.h>
#include <math.h>

// Problem constants (fixed by reference setup_inputs)
constexpr int B = 64;
constexpr int S = 1024;
constexpr int D = 256;
constexpr int NNEG = 32;
constexpr int GPB = 16;                 // groups (blocks) per chain in K1
constexpr int G1 = B * GPB;             // 1024 partial blocks
constexpr int RPB = S / GPB;            // 64 rows per K1 block
constexpr int NPAIR = B * (B - 1) / 2;  // 2016

// ---- DPP wave64 sum: 6 VALU ops, zero DS-pipe traffic ----
template <int CTRL, int RM>
__device__ __forceinline__ float dppadd(float v) {
    return v + __int_as_float(__builtin_amdgcn_update_dpp(
                   0, __float_as_int(v), CTRL, RM, 0xf, true));
}
// returns the 64-lane total as a wave-uniform (SGPR) value
__device__ __forceinline__ float wave_sum_dpp(float v) {
    v = dppadd<0x111, 0xf>(v);   // row_shr:1
    v = dppadd<0x112, 0xf>(v);   // row_shr:2
    v = dppadd<0x114, 0xf>(v);   // row_shr:4
    v = dppadd<0x118, 0xf>(v);   // row_shr:8  -> lane15 of each row16 = row sum
    v = dppadd<0x142, 0xa>(v);   // row_bcast:15 into rows 1,3
    v = dppadd<0x143, 0xc>(v);   // row_bcast:31 into rows 2,3 -> lane63 = total
    return __int_as_float(__builtin_amdgcn_readlane(__float_as_int(v), 63));
}

// ================= K1: 64-row partials, software-pipelined loads =============
// 1024 blocks x 256 thr (4 waves). Wave w: 16 rows as 4 groups of 4,
// group n+1 loads issued BEFORE group n compute (double-buffered registers).
// Block 1024: hard-negative row means + zeroes the k2fin counter.
__global__ __launch_bounds__(256) void k1(const float* __restrict__ x,
                                          const float* __restrict__ neg,
                                          float* __restrict__ pblk,
                                          float* __restrict__ praw,
                                          float* __restrict__ lnn,
                                          int* __restrict__ ctr) {
    const int blk  = blockIdx.x;
    const int t    = threadIdx.x;
    const int wave = t >> 6;            // 0..3
    const int lane = t & 63;

    if (blk == G1) {
        __shared__ float nn8[NNEG][8];
        if (t == 0) ctr[0] = 0;               // reset k2fin's arrival counter
        const int k = t >> 3, part = t & 7;   // 32 rows x 8 parts
        const float4* p4 = (const float4*)(neg + k * D + part * 32);
        float s = 0.f;
        #pragma unroll
        for (int e = 0; e < 8; ++e) {
            const float4 v = p4[e];
            s += v.x + v.y + v.z + v.w;
        }
        nn8[k][part] = s;
        __syncthreads();
        if (t < NNEG) {
            float ss = 0.f;
            #pragma unroll
            for (int e = 0; e < 8; ++e) ss += nn8[t][e];
            lnn[t] = ss / (float)D;
        }
        return;
    }

    __shared__ float sacc[4][D + 4];
    __shared__ float sps[4];

    const int b = blk >> 4;             // chain
    const int g = blk & 15;             // group of 64 rows
    // wave w owns rows [w*16, w*16+16) of this block's 64-row window
    const float* rowp = x + ((size_t)b * S + (size_t)g * RPB + wave * 16) * D + lane * 4;

    float ax = 0.f, ay = 0.f, az = 0.f, aw = 0.f, ps = 0.f;

    // prologue: load group 0
    float4 c0 = *(const float4*)(rowp + (size_t)0 * D);
    float4 c1 = *(const float4*)(rowp + (size_t)1 * D);
    float4 c2 = *(const float4*)(rowp + (size_t)2 * D);
    float4 c3 = *(const float4*)(rowp + (size_t)3 * D);

    #pragma unroll
    for (int grp = 0; grp < 4; ++grp) {
        float4 n0, n1, n2, n3;
        if (grp < 3) {  // prefetch next group before computing current
            const float* np = rowp + (size_t)(grp + 1) * 4 * D;
            n0 = *(const float4*)(np + (size_t)0 * D);
            n1 = *(const float4*)(np + (size_t)1 * D);
            n2 = *(const float4*)(np + (size_t)2 * D);
            n3 = *(const float4*)(np + (size_t)3 * D);
        }

        const float s0 = wave_sum_dpp(c0.x * c0.x + c0.y * c0.y + c0.z * c0.z + c0.w * c0.w);
        const float s1 = wave_sum_dpp(c1.x * c1.x + c1.y * c1.y + c1.z * c1.z + c1.w * c1.w);
        const float s2 = wave_sum_dpp(c2.x * c2.x + c2.y * c2.y + c2.z * c2.z + c2.w * c2.w);
        const float s3 = wave_sum_dpp(c3.x * c3.x + c3.y * c3.y + c3.z * c3.z + c3.w * c3.w);

        // 1/max(sqrt(ss),1e-8) == rsq(max(ss,1e-16)); single v_rsq_f32
        const float i0 = __builtin_amdgcn_rsqf(fmaxf(s0, 1e-16f));
        const float i1 = __builtin_amdgcn_rsqf(fmaxf(s1, 1e-16f));
        const float i2 = __builtin_amdgcn_rsqf(fmaxf(s2, 1e-16f));
        const float i3 = __builtin_amdgcn_rsqf(fmaxf(s3, 1e-16f));

        ax += c0.x * i0 + c1.x * i1 + c2.x * i2 + c3.x * i3;
        ay += c0.y * i0 + c1.y * i1 + c2.y * i2 + c3.y * i3;
        az += c0.z * i0 + c1.z * i1 + c2.z * i2 + c3.z * i3;
        aw += c0.w * i0 + c1.w * i1 + c2.w * i2 + c3.w * i3;
        ps += (c0.x + c0.y + c0.z + c0.w) + (c1.x + c1.y + c1.z + c1.w) +
              (c2.x + c2.y + c2.z + c2.w) + (c3.x + c3.y + c3.z + c3.w);

        if (grp < 3) { c0 = n0; c1 = n1; c2 = n2; c3 = n3; }
    }

    *(float4*)&sacc[wave][lane * 4] = make_float4(ax, ay, az, aw);
    const float pst = wave_sum_dpp(ps);
    if (lane == 0) sps[wave] = pst;
    __syncthreads();

    {
        const float v = sacc[0][t] + sacc[1][t] + sacc[2][t] + sacc[3][t];
        pblk[(size_t)blk * D + t] = v;
    }
    if (t == 0) praw[blk] = sps[0] + sps[1] + sps[2] + sps[3];
}

// ================= K1b: chain reduce -> cs, sq, pm ===========================
// 64 blocks x 256 thr; thread t = dim t.
__global__ __launch_bounds__(256) void k1b(const float* __restrict__ pblk,
                                           const float* __restrict__ praw,
                                           float* __restrict__ cs,
                                           float* __restrict__ sq,
                                           float* __restrict__ pm) {
    const int b    = blockIdx.x;
    const int t    = threadIdx.x;
    const int wave = t >> 6;
    const int lane = t & 63;

    __shared__ float red[4];

    float v = 0.f;
    #pragma unroll
    for (int g = 0; g < GPB; ++g) v += pblk[(size_t)(b * GPB + g) * D + t];
    cs[(size_t)b * D + t] = v;

    const float s2 = wave_sum_dpp(v * v);
    if (lane == 0) red[wave] = s2;
    __syncthreads();
    if (t == 0) sq[b] = red[0] + red[1] + red[2] + red[3];

    if (wave == 0) {
        float s = (lane < GPB) ? praw[b * GPB + lane] : 0.f;
        const float tot = wave_sum_dpp(s);
        if (lane == 0) pm[b] = tot / (float)(S * D);
    }
}

// ================= K2fin: Gram row + last-block finalize =====================
__device__ __forceinline__ float block_sum256(float v, volatile float* red,
                                              int wave, int lane) {
    const float w = wave_sum_dpp(v);
    if (lane == 0) red[wave] = w;
    __syncthreads();
    const float r = red[0] + red[1] + red[2] + red[3];
    __syncthreads();
    return r;
}

__global__ __launch_bounds__(256) void k2fin(const float* __restrict__ cs,
                                             const float* __restrict__ sq,
                                             const float* __restrict__ pm,
                                             const float* __restrict__ lnn,
                                             float* __restrict__ inter_part,
                                             int* __restrict__ ctr,
                                             float* __restrict__ out) {
    const int b    = blockIdx.x;
    const int t    = threadIdx.x;
    const int wave = t >> 6;
    const int lane = t & 63;

    __shared__ float red[4];
    __shared__ int   role;

    // Gram row b: waves stride over columns j > b
    {
        const float invS2 = 1.0f / ((float)S * (float)S);
        const float4 a = *(const float4*)(cs + (size_t)b * D + lane * 4);
        float my = 0.f;
        for (int j = b + 1 + wave; j < B; j += 4) {
            const float4 bb = *(const float4*)(cs + (size_t)j * D + lane * 4);
            const float dot = wave_sum_dpp(a.x * bb.x + a.y * bb.y +
                                           a.z * bb.z + a.w * bb.w);
            my += fminf(dot * invS2, 1.0f);
        }
        // my is wave-uniform (built from uniform dots)
        if (lane == 0) red[wave] = my;
        __syncthreads();
        if (t == 0) inter_part[b] = red[0] + red[1] + red[2] + red[3];
        __syncthreads();
    }

    // last-block handoff (single atomic per block, no spin)
    if (t == 0) {
        __threadfence();  // release our inter_part store device-wide
        const int old = __hip_atomic_fetch_add(ctr, 1, __ATOMIC_ACQ_REL,
                                               __HIP_MEMORY_SCOPE_AGENT);
        role = (old == B - 1) ? 1 : 0;
    }
    __syncthreads();
    if (!role) return;

    // ---- finalize (winner block only; values independent of winner id) ----
    float my_inter = 0.f, my_intra = 0.f;
    if (t < B) {
        my_inter = inter_part[t];
        my_intra = fminf((sq[t] - (float)S) / ((float)S * (float)(S - 1)), 1.0f);
    }

    float my_hard = 0.f;
    for (int k = t; k < B * NNEG; k += 256) {
        const int bb = k >> 5, nk = k & 31;
        my_hard += fmaxf(lnn[nk] - pm[bb] + 1.0f, 0.f);
    }

    const float intra = block_sum256(my_intra, red, wave, lane) / (float)B;
    const float inter = block_sum256(my_inter, red, wave, lane) / (float)NPAIR;
    const float hard  = block_sum256(my_hard,  red, wave, lane) / (float)(B * NNEG);

    if (t == 0) {
        out[0] = intra;
        out[1] = inter;
        out[2] = hard;
        out[3] = intra + inter + 0.1f * hard;
    }
}

extern "C" void kernel_launch(void* const* d_in, const int* in_sizes, int n_in,
                              void* d_out, int out_size, void* d_ws, size_t ws_size,
                              hipStream_t stream) {
    const float* x   = (const float*)d_in[0];   // [B, S, D]
    const float* neg = (const float*)d_in[1];   // [NNEG, D]
    float* out = (float*)d_out;

    int*   ctr = (int*)d_ws;                    // zeroed by k1's extra block
    float* wf  = (float*)((char*)d_ws + 256);
    float* pblk       = wf;                          // G1*D = 262144
    float* praw       = pblk + (size_t)G1 * D;       // G1
    float* cs         = praw + G1;                   // B*D
    float* sq         = cs + (size_t)B * D;          // B
    float* pm         = sq + B;                      // B
    float* lnn        = pm + B;                      // NNEG
    float* inter_part = lnn + NNEG;                  // B

    k1<<<G1 + 1, 256, 0, stream>>>(x, neg, pblk, praw, lnn, ctr);
    k1b<<<B, 256, 0, stream>>>(pblk, praw, cs, sq, pm);
    k2fin<<<B, 256, 0, stream>>>(cs, sq, pm, lnn, inter_part, ctr, out);
}